// Round 3
// baseline (168.181 us; speedup 1.0000x reference)
//
#include <hip/hip_runtime.h>
#include <math.h>
#include <stdint.h>

#define NS    16
#define HWSZ  409600
#define NW    6400        // mask words per sample (HWSZ/64)
#define NBIN  512
#define CAP   2048
#define SBPS  200         // scan blocks per sample (2048 elems each)
#define GBPS  100         // gather blocks per sample (4096 elems each)

typedef unsigned long long u64;

__device__ __forceinline__ unsigned fkey(float f) {
    unsigned u = __float_as_uint(f);
    if (u == 0x80000000u) u = 0u;                 // canonicalize -0
    return (u & 0x80000000u) ? ~u : (u | 0x80000000u);
}

// bce1: BCE on p; bce2: BCE on sigmoid(50(p-t)); both with 1e-7 clipping
__device__ __forceinline__ void bce_pair(float pv, float tv, bool tc, float& o1, float& o2) {
    float pc = fminf(fmaxf(pv, 1e-7f), 1.0f - 1e-7f);
    float a = tc ? pc : 1.0f - pc;
    o1 = -__logf(a);
    float x = 50.0f * (pv - tv);
    float y = tc ? -x : x;
    float t2 = __expf(-fabsf(y));
    float sp = __logf(1.0f + t2);
    sp = (y > 0.0f) ? y + sp : sp;
    o2 = fminf(sp, 16.118095651f);
}

__device__ __forceinline__ int pbin(float p) {
    int b = (int)(p * (float)NBIN);
    return min(max(b, 0), NBIN - 1);
}

// Wave-parallel descending k-th-largest bin search over a histogram.
__device__ __forceinline__ bool wave_find(const int* __restrict__ h, int nbins, int k,
                                          int* bin_out, int* rank_out) {
    const int lane = threadIdx.x & 63;
    const int CH = nbins >> 6;
    const int topStart = nbins - 1 - lane * CH;
    int s = 0;
    for (int b = 0; b < CH; ++b) s += h[topStart - b];
    int incl = s;
    for (int off = 1; off < 64; off <<= 1) {
        int v = __shfl_up(incl, off, 64);
        if (lane >= off) incl += v;
    }
    int before = incl - s;
    if (before < k && k <= incl) {
        int c = before;
        for (int b = 0; b < CH; ++b) {
            int hb = h[topStart - b];
            c += hb;
            if (c >= k) { *bin_out = topStart - b; *rank_out = k - (c - hb); return true; }
        }
    }
    return false;
}

// ---------------- fat pass --------------------------------------------------
__global__ void k_scan1(const float* __restrict__ outputs, const float* __restrict__ labels,
                        const float* __restrict__ tmask, const float* __restrict__ gd,
                        int* __restrict__ hcnt, float* __restrict__ hs1, float* __restrict__ hs2,
                        u64* __restrict__ maskw,
                        int* __restrict__ cnt_pos, int* __restrict__ cnt_neg,
                        double* __restrict__ psum, double* __restrict__ acc) {
    __shared__ int lc[NBIN];
    __shared__ float l1[NBIN], l2[NBIN];
    __shared__ double rd[4][4];
    __shared__ int ri[4][2];
    const int t = threadIdx.x, n = blockIdx.y;
    for (int i = t; i < NBIN; i += 256) { lc[i] = 0; l1[i] = 0.f; l2[i] = 0.f; }
    __syncthreads();
    const float4* P  = (const float4*)(outputs + (size_t)n * 2 * HWSZ);
    const float4* Th = P + HWSZ / 4;
    const float4* G  = (const float4*)(labels + (size_t)n * 2 * HWSZ);
    const float4* Gt = G + HWSZ / 4;
    const float4* T  = (const float4*)(tmask + (size_t)n * HWSZ);
    const float4* D  = (const float4*)(gd + (size_t)n * HWSZ);
    u64* Mw = maskw + (size_t)n * NW;
    const int base4 = blockIdx.x * 512;
    const int lane = t & 63;
    const int i4a = base4 + t, i4b = i4a + 256;
    // issue all 12 loads up-front for ILP
    float4 pA = P[i4a],  pB = P[i4b];
    float4 tA = Th[i4a], tB = Th[i4b];
    float4 gA = G[i4a],  gB = G[i4b];
    float4 qA = Gt[i4a], qB = Gt[i4b];
    float4 mA = T[i4a],  mB = T[i4b];
    float4 dA = D[i4a],  dB = D[i4b];
    float s3 = 0.f, s4 = 0.f, p1 = 0.f, p2 = 0.f;
    int cp = 0, cn = 0;
    auto proc = [&](const float4& p, const float4& th, const float4& g, const float4& q,
                    const float4& m, const float4& d, int i4) {
        const float* pp = (const float*)&p;  const float* tt = (const float*)&th;
        const float* gg = (const float*)&g;  const float* qq = (const float*)&q;
        const float* mm = (const float*)&m;  const float* dd = (const float*)&d;
        const int wbase = (i4 >> 6) << 2;
#pragma unroll
        for (int e = 0; e < 4; ++e) {
            float pv = pp[e], tv = tt[e], gv = gg[e], qv = qq[e], mv = mm[e], dv = dd[e];
            s3 += fabsf(tv - qv) * dv;
            s4 += dv;
            bool msk = mv > 0.5f, tc = gv > 0.5f;
            bool neg = msk && !tc;
            u64 mb = __ballot(neg);
            if (!lane) Mw[wbase + e] = mb;
            if (msk) {
                float b1v, b2v; bce_pair(pv, tv, tc, b1v, b2v);
                if (tc) { p1 += b1v; p2 += b2v; cp++; }
                else {
                    cn++;
                    int b = pbin(pv);
                    atomicAdd(&lc[b], 1);
                    atomicAdd(&l1[b], b1v);
                    atomicAdd(&l2[b], b2v);
                }
            }
        }
    };
    proc(pA, tA, gA, qA, mA, dA, i4a);
    proc(pB, tB, gB, qB, mB, dB, i4b);
    double v[4] = {(double)p1, (double)p2, (double)s3, (double)s4};
    for (int off = 32; off; off >>= 1) {
#pragma unroll
        for (int i = 0; i < 4; ++i) v[i] += __shfl_down(v[i], off, 64);
        cp += __shfl_down(cp, off, 64);
        cn += __shfl_down(cn, off, 64);
    }
    const int wid = t >> 6;
    if (!lane) {
#pragma unroll
        for (int i = 0; i < 4; ++i) rd[wid][i] = v[i];
        ri[wid][0] = cp; ri[wid][1] = cn;
    }
    __syncthreads();
    if (!t) {
        atomicAdd(&psum[n * 2 + 0], rd[0][0] + rd[1][0] + rd[2][0] + rd[3][0]);
        atomicAdd(&psum[n * 2 + 1], rd[0][1] + rd[1][1] + rd[2][1] + rd[3][1]);
        atomicAdd(&acc[0], rd[0][2] + rd[1][2] + rd[2][2] + rd[3][2]);
        atomicAdd(&acc[1], rd[0][3] + rd[1][3] + rd[2][3] + rd[3][3]);
        int a = ri[0][0] + ri[1][0] + ri[2][0] + ri[3][0];
        int b = ri[0][1] + ri[1][1] + ri[2][1] + ri[3][1];
        if (a) atomicAdd(&cnt_pos[n], a);
        if (b) atomicAdd(&cnt_neg[n], b);
    }
    int* GH = hcnt + n * NBIN;
    float* G1 = hs1 + n * NBIN;
    float* G2 = hs2 + n * NBIN;
    for (int i = t; i < NBIN; i += 256) {
        int c = lc[i];
        if (c) { atomicAdd(&GH[i], c); atomicAdd(&G1[i], l1[i]); atomicAdd(&G2[i], l2[i]); }
    }
}

// ---------------- per-sample select + suffix sums ---------------------------
__global__ void k_sel1(const int* __restrict__ cnt_pos, const int* __restrict__ cnt_neg,
                       const int* __restrict__ hcnt, const float* __restrict__ hs1,
                       const float* __restrict__ hs2,
                       int* __restrict__ mode, int* __restrict__ b1o, int* __restrict__ k1o,
                       float* __restrict__ ab1, float* __restrict__ ab2, int* __restrict__ abc) {
    const int n = blockIdx.x, lane = threadIdx.x;
    __shared__ int sb1, sk1;
    const int pos = cnt_pos[n], neg = cnt_neg[n];
    int k = pos * 3; if (k > neg) k = neg;
    const int md = (pos == 0) ? 2 : ((k == 0) ? 1 : 0);
    if (!lane) mode[n] = md;
    if (md == 1) { if (!lane) { ab1[n] = 0.f; ab2[n] = 0.f; abc[n] = 0; } return; }
    const int* h = hcnt + n * NBIN;
    int B = -1;
    if (md == 0) {
        int bin, r;
        if (wave_find(h, NBIN, k, &bin, &r)) { sb1 = bin; sk1 = r; }
        __syncthreads();
        B = sb1;
        if (!lane) { b1o[n] = sb1; k1o[n] = sk1; }
    }
    const float* H1 = hs1 + n * NBIN;
    const float* H2 = hs2 + n * NBIN;
    float a1 = 0.f, a2 = 0.f; int ac = 0;
    for (int b = lane; b < NBIN; b += 64)
        if (b > B) { a1 += H1[b]; a2 += H2[b]; ac += h[b]; }
    for (int off = 32; off; off >>= 1) {
        a1 += __shfl_down(a1, off, 64);
        a2 += __shfl_down(a2, off, 64);
        ac += __shfl_down(ac, off, 64);
    }
    if (!lane) { ab1[n] = a1; ab2[n] = a2; abc[n] = ac; }
}

// ---------------- boundary-bin candidate gather (mask + prob only) ----------
__global__ void k_gather(const float* __restrict__ outputs, const u64* __restrict__ maskw,
                         const int* __restrict__ mode, const int* __restrict__ b1a,
                         int* __restrict__ cand_cnt, unsigned* __restrict__ ck,
                         float* __restrict__ cv1, float* __restrict__ cv2) {
    const int n = blockIdx.y;
    if (mode[n] != 0) return;
    const int b1n = b1a[n];
    const int t = threadIdx.x, lane = t & 63, w = t >> 6;
    const float* base = outputs + (size_t)n * 2 * HWSZ;
    const float4* P = (const float4*)base;
    const float* Thp = base + HWSZ;
    const u64* Mw = maskw + (size_t)n * NW;
    const int base4 = blockIdx.x * 1024;
    for (int j = 0; j < 4; ++j) {
        const int i4 = base4 + j * 256 + t;
        float4 p = P[i4];
        const float* pp = (const float*)&p;
        const int wb = ((base4 >> 6) + j * 4 + w) << 2;
#pragma unroll
        for (int e = 0; e < 4; ++e) {
            u64 W = Mw[wb + e];
            bool neg = (W >> lane) & 1ull;
            bool cand = neg && (pbin(pp[e]) == b1n);
            u64 mb = __ballot(cand);
            if (cand) {
                float tv = Thp[4 * i4 + e];
                float b1v, b2v; bce_pair(pp[e], tv, false, b1v, b2v);
                int leader = __ffsll(mb) - 1;
                int cnt = __popcll(mb);
                int off = __popcll(mb & ((1ull << lane) - 1ull));
                int bidx = 0;
                if (lane == leader) bidx = atomicAdd(&cand_cnt[n], cnt);
                bidx = __shfl(bidx, leader, 64);
                int idx = bidx + off;
                if (idx < CAP) {
                    ck [n * CAP + idx] = fkey(pp[e]);
                    cv1[n * CAP + idx] = b1v;
                    cv2[n * CAP + idx] = b2v;
                }
            }
        }
    }
}

// ---------------- per-sample finalize ---------------------------------------
__global__ void k_final(const float* __restrict__ outputs, const u64* __restrict__ maskw,
                        const int* __restrict__ mode, const int* __restrict__ b1a,
                        const int* __restrict__ k1a, const int* __restrict__ cnt_pos,
                        const int* __restrict__ cand_cnt, const unsigned* __restrict__ ck,
                        const float* __restrict__ cv1, const float* __restrict__ cv2,
                        const double* __restrict__ psum, const float* __restrict__ ab1,
                        const float* __restrict__ ab2, const int* __restrict__ abc,
                        double* __restrict__ acc) {
    __shared__ unsigned sk[CAP];
    __shared__ float sv1[CAP], sv2[CAP];
    __shared__ int h[2048];
    __shared__ int sbh, srh, sbm, srm, sbl;
    __shared__ double rd[4][2];
    __shared__ int ri[4];
    const int n = blockIdx.x, t = threadIdx.x;
    const int md = mode[n];
    double f1r = 0.0, f2r = 0.0; int fcr = 0;
    if (md == 0) {
        const int k1 = k1a[n];
        const int cc = cand_cnt[n];
        float f1 = 0.f, f2 = 0.f; int fc = 0;
        if (cc <= CAP) {
            for (int i = t; i < cc; i += 256) {
                sk[i] = ck[n * CAP + i]; sv1[i] = cv1[n * CAP + i]; sv2[i] = cv2[n * CAP + i];
            }
            for (int i = t; i < 2048; i += 256) h[i] = 0;
            __syncthreads();
            for (int i = t; i < cc; i += 256) atomicAdd(&h[sk[i] >> 21], 1);
            __syncthreads();
            if (t < 64) { int b, r; if (wave_find(h, 2048, k1, &b, &r)) { sbh = b; srh = r; } }
            __syncthreads();
            const unsigned bh = (unsigned)sbh; const int r2 = srh;
            for (int i = t; i < 2048; i += 256) h[i] = 0;
            __syncthreads();
            for (int i = t; i < cc; i += 256)
                if ((sk[i] >> 21) == bh) atomicAdd(&h[(sk[i] >> 10) & 0x7FFu], 1);
            __syncthreads();
            if (t < 64) { int b, r; if (wave_find(h, 2048, r2, &b, &r)) { sbm = b; srm = r; } }
            __syncthreads();
            const unsigned bm = (unsigned)sbm; const int r3 = srm;
            for (int i = t; i < 1024; i += 256) h[i] = 0;
            __syncthreads();
            for (int i = t; i < cc; i += 256)
                if ((sk[i] >> 10) == ((bh << 11) | bm)) atomicAdd(&h[sk[i] & 0x3FFu], 1);
            __syncthreads();
            if (t < 64) { int b, r; if (wave_find(h, 1024, r3, &b, &r)) sbl = b; }
            __syncthreads();
            const unsigned thr_key = (bh << 21) | (bm << 10) | (unsigned)sbl;
            for (int i = t; i < cc; i += 256)
                if (sk[i] >= thr_key) { f1 += sv1[i]; f2 += sv2[i]; fc++; }
        } else {
            // slow path: rescan boundary bin from global (general insurance)
            const int b1n = b1a[n];
            const float* Pp = outputs + (size_t)n * 2 * HWSZ;
            const float* Thp = Pp + HWSZ;
            const u64* Mw = maskw + (size_t)n * NW;
            auto negat = [&](int i) -> bool {
                u64 W = Mw[((i >> 8) << 2) | (i & 3)];
                return (W >> ((i >> 2) & 63)) & 1ull;
            };
            for (int i = t; i < 2048; i += 256) h[i] = 0;
            __syncthreads();
            for (int i = t; i < HWSZ; i += 256)
                if (negat(i)) { float pv = Pp[i];
                    if (pbin(pv) == b1n) atomicAdd(&h[fkey(pv) >> 21], 1); }
            __syncthreads();
            if (t < 64) { int b, r; if (wave_find(h, 2048, k1, &b, &r)) { sbh = b; srh = r; } }
            __syncthreads();
            const unsigned bh = (unsigned)sbh; const int r2 = srh;
            for (int i = t; i < 2048; i += 256) h[i] = 0;
            __syncthreads();
            for (int i = t; i < HWSZ; i += 256)
                if (negat(i)) { float pv = Pp[i]; unsigned key = fkey(pv);
                    if (pbin(pv) == b1n && (key >> 21) == bh)
                        atomicAdd(&h[(key >> 10) & 0x7FFu], 1); }
            __syncthreads();
            if (t < 64) { int b, r; if (wave_find(h, 2048, r2, &b, &r)) { sbm = b; srm = r; } }
            __syncthreads();
            const unsigned bm = (unsigned)sbm; const int r3 = srm;
            for (int i = t; i < 1024; i += 256) h[i] = 0;
            __syncthreads();
            for (int i = t; i < HWSZ; i += 256)
                if (negat(i)) { float pv = Pp[i]; unsigned key = fkey(pv);
                    if (pbin(pv) == b1n && (key >> 10) == ((bh << 11) | bm))
                        atomicAdd(&h[key & 0x3FFu], 1); }
            __syncthreads();
            if (t < 64) { int b, r; if (wave_find(h, 1024, r3, &b, &r)) sbl = b; }
            __syncthreads();
            const unsigned thr_key = (bh << 21) | (bm << 10) | (unsigned)sbl;
            for (int i = t; i < HWSZ; i += 256)
                if (negat(i)) { float pv = Pp[i];
                    if (pbin(pv) == b1n && fkey(pv) >= thr_key) {
                        float b1v, b2v; bce_pair(pv, Thp[i], false, b1v, b2v);
                        f1 += b1v; f2 += b2v; fc++;
                    } }
        }
        double v0 = f1, v1 = f2;
        for (int off = 32; off; off >>= 1) {
            v0 += __shfl_down(v0, off, 64);
            v1 += __shfl_down(v1, off, 64);
            fc += __shfl_down(fc, off, 64);
        }
        const int lane = t & 63, wid = t >> 6;
        if (!lane) { rd[wid][0] = v0; rd[wid][1] = v1; ri[wid] = fc; }
        __syncthreads();
        if (!t) {
            f1r = rd[0][0] + rd[1][0] + rd[2][0] + rd[3][0];
            f2r = rd[0][1] + rd[1][1] + rd[2][1] + rd[3][1];
            fcr = ri[0] + ri[1] + ri[2] + ri[3];
        }
    }
    if (!t) {
        double add1 = psum[n * 2 + 0] + (double)ab1[n] + f1r;
        double add2 = psum[n * 2 + 1] + (double)ab2[n] + f2r;
        double addc = (double)cnt_pos[n] + (double)abc[n] + (double)fcr;
        atomicAdd(&acc[2], add1);
        atomicAdd(&acc[3], add2);
        atomicAdd(&acc[4], addc);
    }
}

__global__ void k_fin(const double* __restrict__ acc, float* __restrict__ out) {
    if (threadIdx.x != 0 || blockIdx.x != 0) return;
    double msum = acc[4];
    double lp = (msum > 0.0) ? acc[2] / msum : 0.0;
    double lb = (msum > 0.0) ? acc[3] / msum : 0.0;
    double lt = acc[0] / (acc[1] + 1e-6);
    out[0] = (float)(lp + lb + 10.0 * lt);
    out[1] = (float)lp;
    out[2] = (float)lb;
    out[3] = (float)lt;
}

extern "C" void kernel_launch(void* const* d_in, const int* in_sizes, int n_in,
                              void* d_out, int out_size, void* d_ws, size_t ws_size,
                              hipStream_t stream) {
    const float* outputs = (const float*)d_in[0];
    const float* labels  = (const float*)d_in[1];
    const float* tmask   = (const float*)d_in[2];
    const float* gd      = (const float*)d_in[3];
    float* out = (float*)d_out;

    char* ws = (char*)d_ws;
    double* acc   = (double*)ws;                 // 8
    double* psum  = acc + 8;                     // NS*2
    float* ab1    = (float*)(psum + NS * 2);     // NS
    float* ab2    = ab1 + NS;                    // NS
    int* cnt_pos  = (int*)(ab2 + NS);            // NS
    int* cnt_neg  = cnt_pos + NS;
    int* mode     = cnt_neg + NS;
    int* b1       = mode + NS;
    int* k1       = b1 + NS;
    int* cand_cnt = k1 + NS;
    int* abc      = cand_cnt + NS;
    int* hcnt     = abc + NS;                    // NS*NBIN
    float* hs1    = (float*)(hcnt + NS * NBIN);  // NS*NBIN
    float* hs2    = hs1 + NS * NBIN;             // NS*NBIN
    unsigned* ck  = (unsigned*)(hs2 + NS * NBIN);// NS*CAP (not zeroed)
    float* cv1    = (float*)(ck + NS * CAP);
    float* cv2    = cv1 + NS * CAP;
    u64* maskw    = (u64*)(cv2 + NS * CAP);      // NS*NW (fully written)
    (void)ws_size; (void)in_sizes; (void)n_in; (void)out_size;
    size_t zbytes = (size_t)((char*)ck - ws);

    hipMemsetAsync(d_ws, 0, zbytes, stream);

    k_scan1<<<dim3(SBPS, NS), 256, 0, stream>>>(outputs, labels, tmask, gd,
                                                hcnt, hs1, hs2, maskw, cnt_pos, cnt_neg, psum, acc);
    k_sel1<<<NS, 64, 0, stream>>>(cnt_pos, cnt_neg, hcnt, hs1, hs2, mode, b1, k1, ab1, ab2, abc);
    k_gather<<<dim3(GBPS, NS), 256, 0, stream>>>(outputs, maskw, mode, b1, cand_cnt, ck, cv1, cv2);
    k_final<<<NS, 256, 0, stream>>>(outputs, maskw, mode, b1, k1, cnt_pos, cand_cnt,
                                    ck, cv1, cv2, psum, ab1, ab2, abc, acc);
    k_fin<<<1, 64, 0, stream>>>(acc, out);
}